// Round 1
// baseline (292.960 us; speedup 1.0000x reference)
//
#include <hip/hip_runtime.h>
#include <hip/hip_bf16.h>

#define LL 50
#define DD 64

__device__ __forceinline__ float rlane(float v, int l) {
  return __uint_as_float(__builtin_amdgcn_readlane(__float_as_uint(v), l));
}

__device__ __forceinline__ float wave_sum(float v) {
#pragma unroll
  for (int m = 32; m >= 1; m >>= 1) v += __shfl_xor(v, m, 64);
  return v;
}

// One-time 64x64 transpose of Wk into workspace (WT[a][b] = W[b][a]).
__global__ void transpose64(const float* __restrict__ W, float* __restrict__ WT) {
  const int lane = threadIdx.x;
#pragma unroll 8
  for (int i = 0; i < DD; ++i) WT[i * DD + lane] = W[lane * DD + i];
}

__global__ __launch_bounds__(64) void vc_agg_kernel(
    const int* __restrict__ nodes,
    const int* __restrict__ hvc,
    const int* __restrict__ hr,
    const float* __restrict__ c2e,
    const float* __restrict__ v2e,
    const float* __restrict__ r2e,
    const float* __restrict__ W1, const float* __restrict__ b1,
    const float* __restrict__ Wq, const float* __restrict__ bq,
    const float* __restrict__ WkT, const float* __restrict__ bk,
    const float* __restrict__ Wv, const float* __restrict__ bv,
    const float* __restrict__ Wo, const float* __restrict__ bo,
    float* __restrict__ out) {
  const int n = blockIdx.x;
  const int lane = threadIdx.x;

  // ---- q[lane] = v2e[nodes[n]] . Wq[:,lane] + bq[lane] ----
  const int node = nodes[n];  // uniform
  const float* __restrict__ vrow = v2e + (size_t)node * DD;
  float q = bq[lane];
  {
    float a0 = 0.f, a1 = 0.f, a2 = 0.f, a3 = 0.f;
#pragma unroll
    for (int e = 0; e < DD; e += 4) {
      a0 = fmaf(vrow[e + 0], Wq[(e + 0) * DD + lane], a0);
      a1 = fmaf(vrow[e + 1], Wq[(e + 1) * DD + lane], a1);
      a2 = fmaf(vrow[e + 2], Wq[(e + 2) * DD + lane], a2);
      a3 = fmaf(vrow[e + 3], Wq[(e + 3) * DD + lane], a3);
    }
    q += (a0 + a1) + (a2 + a3);
  }

  // ---- g[lane] = sum_dp Wk[lane][dp] * q[dp]  (WkT is Wk transposed) ----
  float g;
  {
    float a0 = 0.f, a1 = 0.f, a2 = 0.f, a3 = 0.f;
#pragma unroll
    for (int e = 0; e < DD; e += 4) {
      a0 = fmaf(rlane(q, e + 0), WkT[(e + 0) * DD + lane], a0);
      a1 = fmaf(rlane(q, e + 1), WkT[(e + 1) * DD + lane], a1);
      a2 = fmaf(rlane(q, e + 2), WkT[(e + 2) * DD + lane], a2);
      a3 = fmaf(rlane(q, e + 3), WkT[(e + 3) * DD + lane], a3);
    }
    g = (a0 + a1) + (a2 + a3);
  }
  // cb = q . bk  (uniform across lanes after reduce)
  const float cb = wave_sum(q * bk[lane]);

  // ---- hoist W1 column `lane` into registers (128 VGPRs) ----
  float w1c[2 * DD];
#pragma unroll
  for (int e = 0; e < 2 * DD; ++e) w1c[e] = W1[e * DD + lane];

  const float b1v = b1[lane];
  const int* __restrict__ hv = hvc + (size_t)n * LL;
  const int* __restrict__ hrr = hr + (size_t)n * LL;

  // ---- history loop with fused online softmax ----
  float m = -INFINITY, Z = 0.f, Hacc = 0.f;
#pragma unroll 2
  for (int l = 0; l < LL; ++l) {
    const int vc = hv[l];   // uniform -> s_load
    const int rr = hrr[l];  // uniform -> s_load
    const float* __restrict__ cr = c2e + (size_t)vc * DD;
    const float* __restrict__ rrow = r2e + (size_t)rr * DD;
    float a0 = b1v, a1 = 0.f, a2 = 0.f, a3 = 0.f;
#pragma unroll
    for (int e = 0; e < DD; e += 4) {
      a0 = fmaf(cr[e + 0], w1c[e + 0], a0);
      a1 = fmaf(cr[e + 1], w1c[e + 1], a1);
      a2 = fmaf(cr[e + 2], w1c[e + 2], a2);
      a3 = fmaf(cr[e + 3], w1c[e + 3], a3);
    }
#pragma unroll
    for (int e = 0; e < DD; e += 4) {
      a0 = fmaf(rrow[e + 0], w1c[DD + e + 0], a0);
      a1 = fmaf(rrow[e + 1], w1c[DD + e + 1], a1);
      a2 = fmaf(rrow[e + 2], w1c[DD + e + 2], a2);
      a3 = fmaf(rrow[e + 3], w1c[DD + e + 3], a3);
    }
    const float h = fmaxf((a0 + a1) + (a2 + a3), 0.f);

    // score_l = (h.g + q.bk) / sqrt(64)
    const float p = wave_sum(h * g);
    const float s = (p + cb) * 0.125f;

    // online softmax update (uniform values, computed redundantly per lane)
    const float mn = fmaxf(m, s);
    const float sc = __expf(m - mn);   // exp(-inf)=0 on first iter
    const float el = __expf(s - mn);
    Z = Z * sc + el;
    Hacc = Hacc * sc + el * h;  // per-lane weighted h accumulation
    m = mn;
  }
  Hacc *= (1.f / Z);

  // ---- ctx[lane] = Hacc . Wv[:,lane] + bv[lane]  (sum over attn == 1) ----
  float ctx = bv[lane];
  {
    float a0 = 0.f, a1 = 0.f, a2 = 0.f, a3 = 0.f;
#pragma unroll
    for (int e = 0; e < DD; e += 4) {
      a0 = fmaf(rlane(Hacc, e + 0), Wv[(e + 0) * DD + lane], a0);
      a1 = fmaf(rlane(Hacc, e + 1), Wv[(e + 1) * DD + lane], a1);
      a2 = fmaf(rlane(Hacc, e + 2), Wv[(e + 2) * DD + lane], a2);
      a3 = fmaf(rlane(Hacc, e + 3), Wv[(e + 3) * DD + lane], a3);
    }
    ctx += (a0 + a1) + (a2 + a3);
  }

  // ---- out[lane] = ctx . Wo[:,lane] + bo[lane] ----
  float o = bo[lane];
  {
    float a0 = 0.f, a1 = 0.f, a2 = 0.f, a3 = 0.f;
#pragma unroll
    for (int e = 0; e < DD; e += 4) {
      a0 = fmaf(rlane(ctx, e + 0), Wo[(e + 0) * DD + lane], a0);
      a1 = fmaf(rlane(ctx, e + 1), Wo[(e + 1) * DD + lane], a1);
      a2 = fmaf(rlane(ctx, e + 2), Wo[(e + 2) * DD + lane], a2);
      a3 = fmaf(rlane(ctx, e + 3), Wo[(e + 3) * DD + lane], a3);
    }
    o += (a0 + a1) + (a2 + a3);
  }
  out[(size_t)n * DD + lane] = o;
}

extern "C" void kernel_launch(void* const* d_in, const int* in_sizes, int n_in,
                              void* d_out, int out_size, void* d_ws, size_t ws_size,
                              hipStream_t stream) {
  const int* nodes = (const int*)d_in[0];
  const int* hvc = (const int*)d_in[1];
  const int* hr = (const int*)d_in[2];
  const float* c2e = (const float*)d_in[3];
  const float* v2e = (const float*)d_in[4];
  const float* r2e = (const float*)d_in[5];
  const float* W1 = (const float*)d_in[6];
  const float* b1 = (const float*)d_in[7];
  const float* Wq = (const float*)d_in[8];
  const float* bq = (const float*)d_in[9];
  const float* Wk = (const float*)d_in[10];
  const float* bk = (const float*)d_in[11];
  const float* Wv = (const float*)d_in[12];
  const float* bv = (const float*)d_in[13];
  const float* Wo = (const float*)d_in[14];
  const float* bo = (const float*)d_in[15];
  float* out = (float*)d_out;

  const int N = in_sizes[0];
  float* WkT = (float*)d_ws;  // 64*64*4 = 16 KB

  transpose64<<<1, 64, 0, stream>>>(Wk, WkT);
  vc_agg_kernel<<<N, 64, 0, stream>>>(nodes, hvc, hr, c2e, v2e, r2e, W1, b1,
                                      Wq, bq, WkT, bk, Wv, bv, Wo, bo, out);
}

// Round 3
// 65.481 us; speedup vs baseline: 4.4739x; 4.4739x over previous
//
#include <hip/hip_runtime.h>
#include <hip/hip_bf16.h>

#define LL 50
#define DD 64

// workspace layout (floats)
#define WS_WKT 0            // 64*64
#define WS_A   4096         // 1000*64
#define WS_B   68096        // 5*64
#define WS_WVO 68416        // 64*64
#define WS_BVO 72512        // 64

__device__ __forceinline__ float rlanef(float v, int l) {
  return __uint_as_float(__builtin_amdgcn_readlane(__float_as_uint(v), l));
}
__device__ __forceinline__ float wave_sum(float v) {
#pragma unroll
  for (int m = 32; m >= 1; m >>= 1) v += __shfl_xor(v, m, 64);
  return v;
}
__device__ __forceinline__ float wave_max(float v) {
#pragma unroll
  for (int m = 32; m >= 1; m >>= 1) v = fmaxf(v, __shfl_xor(v, m, 64));
  return v;
}

// One kernel does all precomputes, dispatched by blockIdx:
//  [0,1000)   A[row]  = c2e[row] @ W1[:64]
//  [1000,1005) B[r]   = r2e[r] @ W1[64:] + b1
//  [1005,1069) Wvo[r] = Wv[r] @ Wo
//  1069        bvo    = bv @ Wo + bo
//  1070        WkT    = Wk^T
__global__ __launch_bounds__(64) void prep_kernel(
    const float* __restrict__ c2e, const float* __restrict__ r2e,
    const float* __restrict__ W1, const float* __restrict__ b1,
    const float* __restrict__ Wk, const float* __restrict__ Wv,
    const float* __restrict__ Wo, const float* __restrict__ bv,
    const float* __restrict__ bo, float* __restrict__ ws) {
  const int lane = threadIdx.x;
  const int b = blockIdx.x;
  if (b < 1000) {
    const float* __restrict__ crow = c2e + (size_t)b * DD;
    float a0 = 0.f, a1 = 0.f, a2 = 0.f, a3 = 0.f;
#pragma unroll
    for (int e = 0; e < DD; e += 4) {
      a0 = fmaf(crow[e + 0], W1[(e + 0) * DD + lane], a0);
      a1 = fmaf(crow[e + 1], W1[(e + 1) * DD + lane], a1);
      a2 = fmaf(crow[e + 2], W1[(e + 2) * DD + lane], a2);
      a3 = fmaf(crow[e + 3], W1[(e + 3) * DD + lane], a3);
    }
    ws[WS_A + (size_t)b * DD + lane] = (a0 + a1) + (a2 + a3);
  } else if (b < 1005) {
    const int r = b - 1000;
    const float* __restrict__ rrow = r2e + (size_t)r * DD;
    float a0 = b1[lane], a1 = 0.f, a2 = 0.f, a3 = 0.f;
#pragma unroll
    for (int e = 0; e < DD; e += 4) {
      a0 = fmaf(rrow[e + 0], W1[(DD + e + 0) * DD + lane], a0);
      a1 = fmaf(rrow[e + 1], W1[(DD + e + 1) * DD + lane], a1);
      a2 = fmaf(rrow[e + 2], W1[(DD + e + 2) * DD + lane], a2);
      a3 = fmaf(rrow[e + 3], W1[(DD + e + 3) * DD + lane], a3);
    }
    ws[WS_B + (size_t)r * DD + lane] = (a0 + a1) + (a2 + a3);
  } else if (b < 1069) {
    const int r = b - 1005;
    const float* __restrict__ wrow = Wv + (size_t)r * DD;
    float a0 = 0.f, a1 = 0.f, a2 = 0.f, a3 = 0.f;
#pragma unroll
    for (int e = 0; e < DD; e += 4) {
      a0 = fmaf(wrow[e + 0], Wo[(e + 0) * DD + lane], a0);
      a1 = fmaf(wrow[e + 1], Wo[(e + 1) * DD + lane], a1);
      a2 = fmaf(wrow[e + 2], Wo[(e + 2) * DD + lane], a2);
      a3 = fmaf(wrow[e + 3], Wo[(e + 3) * DD + lane], a3);
    }
    ws[WS_WVO + (size_t)r * DD + lane] = (a0 + a1) + (a2 + a3);
  } else if (b == 1069) {
    float a0 = bo[lane], a1 = 0.f, a2 = 0.f, a3 = 0.f;
#pragma unroll
    for (int e = 0; e < DD; e += 4) {
      a0 = fmaf(bv[e + 0], Wo[(e + 0) * DD + lane], a0);
      a1 = fmaf(bv[e + 1], Wo[(e + 1) * DD + lane], a1);
      a2 = fmaf(bv[e + 2], Wo[(e + 2) * DD + lane], a2);
      a3 = fmaf(bv[e + 3], Wo[(e + 3) * DD + lane], a3);
    }
    ws[WS_BVO + lane] = (a0 + a1) + (a2 + a3);
  } else {
#pragma unroll 8
    for (int i = 0; i < DD; ++i) ws[WS_WKT + i * DD + lane] = Wk[lane * DD + i];
  }
}

__global__ __launch_bounds__(256) void vc_main(
    const int* __restrict__ nodes, const int* __restrict__ hvc,
    const int* __restrict__ hr, const float* __restrict__ v2e,
    const float* __restrict__ Wq, const float* __restrict__ bq,
    const float* __restrict__ bk, const float* __restrict__ ws,
    float* __restrict__ out) {
  const float* __restrict__ WkT = ws + WS_WKT;
  const float* __restrict__ A = ws + WS_A;
  const float* __restrict__ Bt = ws + WS_B;
  const float* __restrict__ Wvo = ws + WS_WVO;
  const float* __restrict__ bvo = ws + WS_BVO;

  __shared__ float Bs[5][68];   // padded B table (banks spread by +4/row)
  __shared__ float gS[4][64];   // per-wave g
  __shared__ float eS[4][52];   // per-wave unnormalized attn weights

  const int tid = threadIdx.x;
  const int wid = tid >> 6;
  const int lane = tid & 63;
  // stage B into padded LDS (320 elements, 256 threads -> strided loop!)
  for (int i = tid; i < 5 * DD; i += 256) Bs[i >> 6][i & 63] = Bt[i];
  __syncthreads();

  const int n = blockIdx.x * 4 + wid;

  // ---- q[lane] = v2e[nodes[n]] . Wq[:,lane] + bq[lane] ----
  const int node = __builtin_amdgcn_readfirstlane(nodes[n]);
  const float* __restrict__ vrow = v2e + (size_t)node * DD;  // uniform -> s_load
  float q = bq[lane];
  {
    float a0 = 0.f, a1 = 0.f, a2 = 0.f, a3 = 0.f;
#pragma unroll
    for (int e = 0; e < DD; e += 4) {
      a0 = fmaf(vrow[e + 0], Wq[(e + 0) * DD + lane], a0);
      a1 = fmaf(vrow[e + 1], Wq[(e + 1) * DD + lane], a1);
      a2 = fmaf(vrow[e + 2], Wq[(e + 2) * DD + lane], a2);
      a3 = fmaf(vrow[e + 3], Wq[(e + 3) * DD + lane], a3);
    }
    q += (a0 + a1) + (a2 + a3);
  }

  // ---- g[lane] = Wk[lane,:] . q  via WkT ----
  float g;
  {
    float a0 = 0.f, a1 = 0.f, a2 = 0.f, a3 = 0.f;
#pragma unroll
    for (int e = 0; e < DD; e += 4) {
      a0 = fmaf(rlanef(q, e + 0), WkT[(e + 0) * DD + lane], a0);
      a1 = fmaf(rlanef(q, e + 1), WkT[(e + 1) * DD + lane], a1);
      a2 = fmaf(rlanef(q, e + 2), WkT[(e + 2) * DD + lane], a2);
      a3 = fmaf(rlanef(q, e + 3), WkT[(e + 3) * DD + lane], a3);
    }
    g = (a0 + a1) + (a2 + a3);
  }
  const float cb = wave_sum(q * bk[lane]);  // q . bk
  gS[wid][lane] = g;

  // ---- scores: lane <-> history slot l (gather A row, h = relu(A+B)) ----
  const size_t hbase = (size_t)n * LL;
  const int lidx = (lane < LL) ? lane : 0;
  const int vcl = hvc[hbase + lidx];
  const int rl = hr[hbase + lidx];
  const float* __restrict__ arow = A + (size_t)vcl * DD;
  float s = 0.f;
#pragma unroll
  for (int d0 = 0; d0 < DD; d0 += 4) {
    const float4 av = *(const float4*)(arow + d0);
    const float4 bv4 = *(const float4*)(&Bs[rl][d0]);
    const float4 gv = *(const float4*)(&gS[wid][d0]);
    s = fmaf(fmaxf(av.x + bv4.x, 0.f), gv.x, s);
    s = fmaf(fmaxf(av.y + bv4.y, 0.f), gv.y, s);
    s = fmaf(fmaxf(av.z + bv4.z, 0.f), gv.z, s);
    s = fmaf(fmaxf(av.w + bv4.w, 0.f), gv.w, s);
  }
  s = (s + cb) * 0.125f;
  s = (lane < LL) ? s : -INFINITY;
  const float m = wave_max(s);
  const float e = __expf(s - m);
  const float Z = wave_sum(e);
  if (lane < LL) eS[wid][lane] = e;
  const float invZ = 1.f / Z;

  // ---- ctx[lane=d] = sum_l e_l * relu(A[vc_l,d]+B[r_l,d]) / Z ----
  float ctx = 0.f;
  const float* __restrict__ eSw = eS[wid];
#pragma unroll 10
  for (int l = 0; l < LL; ++l) {
    const int vc = __builtin_amdgcn_readlane(vcl, l);  // uniform -> SGPR
    const int r = __builtin_amdgcn_readlane(rl, l);
    const float a = A[(size_t)vc * DD + lane];  // coalesced, SGPR base
    const float bb = Bs[r][lane];               // conflict-free ds_read
    const float w = eSw[l];                     // broadcast ds_read
    ctx = fmaf(fmaxf(a + bb, 0.f), w, ctx);
  }
  ctx *= invZ;

  // ---- out[lane] = ctx . Wvo[:,lane] + bvo[lane] ----
  float o = bvo[lane];
  {
    float a0 = 0.f, a1 = 0.f, a2 = 0.f, a3 = 0.f;
#pragma unroll
    for (int ee = 0; ee < DD; ee += 4) {
      a0 = fmaf(rlanef(ctx, ee + 0), Wvo[(ee + 0) * DD + lane], a0);
      a1 = fmaf(rlanef(ctx, ee + 1), Wvo[(ee + 1) * DD + lane], a1);
      a2 = fmaf(rlanef(ctx, ee + 2), Wvo[(ee + 2) * DD + lane], a2);
      a3 = fmaf(rlanef(ctx, ee + 3), Wvo[(ee + 3) * DD + lane], a3);
    }
    o += (a0 + a1) + (a2 + a3);
  }
  out[(size_t)n * DD + lane] = o;
}

extern "C" void kernel_launch(void* const* d_in, const int* in_sizes, int n_in,
                              void* d_out, int out_size, void* d_ws, size_t ws_size,
                              hipStream_t stream) {
  const int* nodes = (const int*)d_in[0];
  const int* hvc = (const int*)d_in[1];
  const int* hr = (const int*)d_in[2];
  const float* c2e = (const float*)d_in[3];
  const float* v2e = (const float*)d_in[4];
  const float* r2e = (const float*)d_in[5];
  const float* W1 = (const float*)d_in[6];
  const float* b1 = (const float*)d_in[7];
  const float* Wq = (const float*)d_in[8];
  const float* bq = (const float*)d_in[9];
  const float* Wk = (const float*)d_in[10];
  const float* bk = (const float*)d_in[11];
  const float* Wv = (const float*)d_in[12];
  const float* bv = (const float*)d_in[13];
  const float* Wo = (const float*)d_in[14];
  const float* bo = (const float*)d_in[15];
  float* out = (float*)d_out;
  float* ws = (float*)d_ws;

  const int N = in_sizes[0];

  prep_kernel<<<1071, 64, 0, stream>>>(c2e, r2e, W1, b1, Wk, Wv, Wo, bv, bo, ws);
  vc_main<<<N / 4, 256, 0, stream>>>(nodes, hvc, hr, v2e, Wq, bq, bk, ws, out);
}

// Round 4
// 47.211 us; speedup vs baseline: 6.2053x; 1.3870x over previous
//
#include <hip/hip_runtime.h>
#include <hip/hip_bf16.h>

#define LL 50
#define DD 64
#define NCATS 1000
#define NRAT 5

// ws byte offsets
#define OFF_H    0          // ushort[1000*5*64] = 640000 B
#define OFF_M1T  640000     // ushort[64*64] bf16 (M1t[d][e] = (Wq Wk^T)[e][d])
#define OFF_WVOT 648192     // ushort[64*64] bf16 (Wvot[d][e] = (Wv Wo)[e][d])
#define OFF_BKQ  656384     // float[64]  (Wk @ bq)
#define OFF_BVO  656640     // float[64]  (bv @ Wo + bo)

typedef __attribute__((ext_vector_type(8))) short short8;
typedef __attribute__((ext_vector_type(4))) float f32x4;

__device__ __forceinline__ float rlanef(float v, int l) {
  return __uint_as_float(__builtin_amdgcn_readlane(__float_as_uint(v), l));
}
__device__ __forceinline__ float wave_sum(float v) {
#pragma unroll
  for (int m = 32; m >= 1; m >>= 1) v += __shfl_xor(v, m, 64);
  return v;
}
__device__ __forceinline__ float wave_max(float v) {
#pragma unroll
  for (int m = 32; m >= 1; m >>= 1) v = fmaxf(v, __shfl_xor(v, m, 64));
  return v;
}
__device__ __forceinline__ unsigned short f2bf(float f) {  // RNE f32->bf16
  unsigned int u = __float_as_uint(f);
  u = (u + 0x7fffu + ((u >> 16) & 1u)) >> 16;
  return (unsigned short)u;
}
__device__ __forceinline__ float bflo(unsigned int u) { return __uint_as_float(u << 16); }
__device__ __forceinline__ float bfhi(unsigned int u) { return __uint_as_float(u & 0xffff0000u); }

// ---------------- prep: all tables, one kernel, independent blocks ----------------
//  [0,1000)     : H[vc][r][d] = bf16(relu(c2e[vc]@W1a + r2e[r]@W1b + b1))
//  [1000,1064)  : M1t[d][e] = bf16( sum_t Wq[e][t] * Wk[d][t] )
//  [1064,1128)  : Wvot[d][e] = bf16( sum_t Wv[e][t] * Wo[t][d] )
//  1128         : bkq[d] = Wk[d]·bq ; bvo[d] = bv·Wo[:,d] + bo[d]
__global__ __launch_bounds__(64) void prep_kernel(
    const float* __restrict__ c2e, const float* __restrict__ r2e,
    const float* __restrict__ W1, const float* __restrict__ b1,
    const float* __restrict__ Wq, const float* __restrict__ bq,
    const float* __restrict__ Wk, const float* __restrict__ Wv,
    const float* __restrict__ Wo, const float* __restrict__ bv,
    const float* __restrict__ bo, char* __restrict__ ws) {
  const int lane = threadIdx.x;
  const int b = blockIdx.x;
  unsigned short* H = (unsigned short*)(ws + OFF_H);
  unsigned short* M1T = (unsigned short*)(ws + OFF_M1T);
  unsigned short* WVOT = (unsigned short*)(ws + OFF_WVOT);
  float* BKQ = (float*)(ws + OFF_BKQ);
  float* BVO = (float*)(ws + OFF_BVO);

  if (b < NCATS) {
    const int vc = b;
    const float* __restrict__ crow = c2e + (size_t)vc * DD;
    float av = 0.f;
#pragma unroll 8
    for (int e = 0; e < DD; ++e) av = fmaf(crow[e], W1[e * DD + lane], av);
#pragma unroll
    for (int r = 0; r < NRAT; ++r) {
      const float* __restrict__ rrow = r2e + (size_t)r * DD;
      float hb = b1[lane];
#pragma unroll 8
      for (int e = 0; e < DD; ++e) hb = fmaf(rrow[e], W1[(DD + e) * DD + lane], hb);
      H[((size_t)vc * NRAT + r) * DD + lane] = f2bf(fmaxf(av + hb, 0.f));
    }
  } else if (b < 1064) {
    const int d = b - 1000;
    float acc = 0.f;
#pragma unroll 8
    for (int t = 0; t < DD; ++t) acc = fmaf(Wq[lane * DD + t], Wk[d * DD + t], acc);
    M1T[d * DD + lane] = f2bf(acc);
  } else if (b < 1128) {
    const int d = b - 1064;
    float acc = 0.f;
#pragma unroll 8
    for (int t = 0; t < DD; ++t) acc = fmaf(Wv[lane * DD + t], Wo[t * DD + d], acc);
    WVOT[d * DD + lane] = f2bf(acc);
  } else {
    float a1 = 0.f, a2 = bo[lane];
#pragma unroll 8
    for (int t = 0; t < DD; ++t) {
      a1 = fmaf(Wk[lane * DD + t], bq[t], a1);
      a2 = fmaf(bv[t], Wo[t * DD + lane], a2);
    }
    BKQ[lane] = a1;
    BVO[lane] = a2;
  }
}

// ---------------- main: 16 nodes per 256-thread block ----------------
__global__ __launch_bounds__(256, 4) void vc_main(
    const int* __restrict__ nodes, const int* __restrict__ hvc,
    const int* __restrict__ hr, const float* __restrict__ v2e,
    const char* __restrict__ ws, float* __restrict__ out, int N) {
  const unsigned short* __restrict__ H = (const unsigned short*)(ws + OFF_H);
  const unsigned short* __restrict__ M1T = (const unsigned short*)(ws + OFF_M1T);
  const unsigned short* __restrict__ WVOT = (const unsigned short*)(ws + OFF_WVOT);
  const float* __restrict__ BKQ = (const float*)(ws + OFF_BKQ);
  const float* __restrict__ BVO = (const float*)(ws + OFF_BVO);

  __shared__ float gS[4][4][64];   // [wave][nn][d]
  __shared__ float ctxS[16][68];   // padded: 272B rows keep 16B alignment, spread banks

  const int tid = threadIdx.x;
  const int wid = tid >> 6;
  const int lane = tid & 63;
  const int kg = lane >> 4;    // k-group 0..3
  const int rw = lane & 15;    // A row / B-C col 0..15
  const int nb = blockIdx.x * 16;

  // ---- A-frag: X = v2e rows of this block's 16 nodes, bf16 ----
  const int node_id = nodes[min(nb + rw, N - 1)];
  const float* __restrict__ xrow = v2e + (size_t)node_id * DD;
  short8 xa[2];
#pragma unroll
  for (int ks = 0; ks < 2; ++ks) {
    const float4 f0 = *(const float4*)(xrow + ks * 32 + kg * 8);
    const float4 f1 = *(const float4*)(xrow + ks * 32 + kg * 8 + 4);
    short8 t;
    t[0] = (short)f2bf(f0.x); t[1] = (short)f2bf(f0.y);
    t[2] = (short)f2bf(f0.z); t[3] = (short)f2bf(f0.w);
    t[4] = (short)f2bf(f1.x); t[5] = (short)f2bf(f1.y);
    t[6] = (short)f2bf(f1.z); t[7] = (short)f2bf(f1.w);
    xa[ks] = t;
  }

  // ---- G = X @ M1 (+bkq later) via MFMA: C row=(lane>>4)*4+r, col=n0*16+rw ----
  f32x4 acc[4];
#pragma unroll
  for (int n0 = 0; n0 < 4; ++n0) {
    f32x4 a = {0.f, 0.f, 0.f, 0.f};
#pragma unroll
    for (int ks = 0; ks < 2; ++ks) {
      const short8 bf = *(const short8*)(M1T + (n0 * 16 + rw) * DD + ks * 32 + kg * 8);
      a = __builtin_amdgcn_mfma_f32_16x16x32_bf16(xa[ks], bf, a, 0, 0, 0);
    }
    acc[n0] = a;
  }

  // wave `wid` owns nodes 4*wid..4*wid+3 = C rows with kg==wid
  if (kg == wid) {
#pragma unroll
    for (int n0 = 0; n0 < 4; ++n0) {
      const float bkqv = BKQ[n0 * 16 + rw];
#pragma unroll
      for (int r = 0; r < 4; ++r) gS[wid][r][n0 * 16 + rw] = acc[n0][r] + bkqv;
    }
  }
  // wave-local produce->consume: no block barrier needed

  // ---- per-node gather phases ----
  for (int nn = 0; nn < 4; ++nn) {
    const int n = nb + wid * 4 + nn;
    const int lidx = (lane < LL) ? lane : 0;
    const int vc = hvc[(size_t)n * LL + lidx];
    const int rr = hr[(size_t)n * LL + lidx];
    const int idx = vc * NRAT + rr;

    // scores: lane=l, dot(H[idx], g) over 64 dims
    const uint4* __restrict__ hp = (const uint4*)(H + (size_t)idx * DD);
    const float4* __restrict__ gp = (const float4*)(&gS[wid][nn][0]);
    float s = 0.f;
#pragma unroll
    for (int c = 0; c < 8; ++c) {
      const uint4 u = hp[c];
      const float4 g0 = gp[2 * c];
      const float4 g1 = gp[2 * c + 1];
      s = fmaf(bflo(u.x), g0.x, s); s = fmaf(bfhi(u.x), g0.y, s);
      s = fmaf(bflo(u.y), g0.z, s); s = fmaf(bfhi(u.y), g0.w, s);
      s = fmaf(bflo(u.z), g1.x, s); s = fmaf(bfhi(u.z), g1.y, s);
      s = fmaf(bflo(u.w), g1.z, s); s = fmaf(bfhi(u.w), g1.w, s);
    }
    s *= 0.125f;                       // q·bk is constant over l -> cancels in softmax
    s = (lane < LL) ? s : -INFINITY;
    const float m = wave_max(s);
    const float e = __expf(s - m);
    const float invZ = 1.f / wave_sum(e);

    // ctx: lane=d, sum_l e_l * H[idx_l][d]
    float cacc = 0.f;
#pragma unroll 10
    for (int l = 0; l < LL; ++l) {
      const int si = __builtin_amdgcn_readlane(idx, l);
      const float el = rlanef(e, l);
      const unsigned short hb = H[(size_t)si * DD + lane];
      cacc = fmaf(__uint_as_float(((unsigned int)hb) << 16), el, cacc);
    }
    ctxS[wid * 4 + nn][lane] = cacc * invZ;
  }
  __syncthreads();

  // ---- OUT = CTX @ Wvo + bvo via MFMA ----
  short8 ca[2];
#pragma unroll
  for (int ks = 0; ks < 2; ++ks) {
    const float* __restrict__ cp = &ctxS[rw][ks * 32 + kg * 8];
    const float4 f0 = *(const float4*)(cp);
    const float4 f1 = *(const float4*)(cp + 4);
    short8 t;
    t[0] = (short)f2bf(f0.x); t[1] = (short)f2bf(f0.y);
    t[2] = (short)f2bf(f0.z); t[3] = (short)f2bf(f0.w);
    t[4] = (short)f2bf(f1.x); t[5] = (short)f2bf(f1.y);
    t[6] = (short)f2bf(f1.z); t[7] = (short)f2bf(f1.w);
    ca[ks] = t;
  }
#pragma unroll
  for (int n0 = 0; n0 < 4; ++n0) {
    f32x4 a = {0.f, 0.f, 0.f, 0.f};
#pragma unroll
    for (int ks = 0; ks < 2; ++ks) {
      const short8 bf = *(const short8*)(WVOT + (n0 * 16 + rw) * DD + ks * 32 + kg * 8);
      a = __builtin_amdgcn_mfma_f32_16x16x32_bf16(ca[ks], bf, a, 0, 0, 0);
    }
    const float bvov = BVO[n0 * 16 + rw];
#pragma unroll
    for (int r = 0; r < 4; ++r) {
      const int node = nb + kg * 4 + r;
      if (node < N) out[(size_t)node * DD + n0 * 16 + rw] = a[r] + bvov;
    }
  }
}

extern "C" void kernel_launch(void* const* d_in, const int* in_sizes, int n_in,
                              void* d_out, int out_size, void* d_ws, size_t ws_size,
                              hipStream_t stream) {
  const int* nodes = (const int*)d_in[0];
  const int* hvc = (const int*)d_in[1];
  const int* hr = (const int*)d_in[2];
  const float* c2e = (const float*)d_in[3];
  const float* v2e = (const float*)d_in[4];
  const float* r2e = (const float*)d_in[5];
  const float* W1 = (const float*)d_in[6];
  const float* b1 = (const float*)d_in[7];
  const float* Wq = (const float*)d_in[8];
  const float* bq = (const float*)d_in[9];
  const float* Wk = (const float*)d_in[10];
  const float* bk = (const float*)d_in[11];  // unused: q·bk cancels in softmax
  const float* Wv = (const float*)d_in[12];
  const float* bv = (const float*)d_in[13];
  const float* Wo = (const float*)d_in[14];
  const float* bo = (const float*)d_in[15];
  (void)bk;
  float* out = (float*)d_out;
  char* ws = (char*)d_ws;

  const int N = in_sizes[0];

  prep_kernel<<<1129, 64, 0, stream>>>(c2e, r2e, W1, b1, Wq, bq, Wk, Wv, Wo, bv, bo, ws);
  vc_main<<<(N + 15) / 16, 256, 0, stream>>>(nodes, hvc, hr, v2e, ws, out, N);
}

// Round 5
// 40.681 us; speedup vs baseline: 7.2014x; 1.1605x over previous
//
#include <hip/hip_runtime.h>
#include <hip/hip_bf16.h>

#define LL 50
#define DD 64
#define NCATS 1000
#define NRAT 5

// ws byte offsets
#define OFF_H    0          // ushort[1000*5*64] = 640000 B
#define OFF_M1T  640000     // ushort[64*64] bf16 (M1t[d][e] = (Wq Wk^T)[e][d])
#define OFF_WVOT 648192     // ushort[64*64] bf16 (Wvot[d][e] = (Wv Wo)[e][d])
#define OFF_BKQ  656384     // float[64]  (Wk @ bq)
#define OFF_BVO  656640     // float[64]  (bv @ Wo + bo)

typedef __attribute__((ext_vector_type(8))) short short8;
typedef __attribute__((ext_vector_type(4))) float f32x4;

__device__ __forceinline__ float rlanef(float v, int l) {
  return __uint_as_float(__builtin_amdgcn_readlane(__float_as_uint(v), l));
}
__device__ __forceinline__ float wave_sum(float v) {
#pragma unroll
  for (int m = 32; m >= 1; m >>= 1) v += __shfl_xor(v, m, 64);
  return v;
}
__device__ __forceinline__ float wave_max(float v) {
#pragma unroll
  for (int m = 32; m >= 1; m >>= 1) v = fmaxf(v, __shfl_xor(v, m, 64));
  return v;
}
__device__ __forceinline__ unsigned short f2bf(float f) {  // RNE f32->bf16
  unsigned int u = __float_as_uint(f);
  u = (u + 0x7fffu + ((u >> 16) & 1u)) >> 16;
  return (unsigned short)u;
}
__device__ __forceinline__ float bflo(unsigned int u) { return __uint_as_float(u << 16); }
__device__ __forceinline__ float bfhi(unsigned int u) { return __uint_as_float(u & 0xffff0000u); }

// ---------------- prep: all tables, one kernel, independent 1-wave blocks ----------------
__global__ __launch_bounds__(64) void prep_kernel(
    const float* __restrict__ c2e, const float* __restrict__ r2e,
    const float* __restrict__ W1, const float* __restrict__ b1,
    const float* __restrict__ Wq, const float* __restrict__ bq,
    const float* __restrict__ Wk, const float* __restrict__ Wv,
    const float* __restrict__ Wo, const float* __restrict__ bv,
    const float* __restrict__ bo, char* __restrict__ ws) {
  const int lane = threadIdx.x;
  const int b = blockIdx.x;
  unsigned short* H = (unsigned short*)(ws + OFF_H);
  unsigned short* M1T = (unsigned short*)(ws + OFF_M1T);
  unsigned short* WVOT = (unsigned short*)(ws + OFF_WVOT);
  float* BKQ = (float*)(ws + OFF_BKQ);
  float* BVO = (float*)(ws + OFF_BVO);

  if (b < NCATS) {
    const int vc = b;
    const float* __restrict__ crow = c2e + (size_t)vc * DD;
    float av = 0.f;
#pragma unroll 8
    for (int e = 0; e < DD; ++e) av = fmaf(crow[e], W1[e * DD + lane], av);
#pragma unroll
    for (int r = 0; r < NRAT; ++r) {
      const float* __restrict__ rrow = r2e + (size_t)r * DD;
      float hb = b1[lane];
#pragma unroll 8
      for (int e = 0; e < DD; ++e) hb = fmaf(rrow[e], W1[(DD + e) * DD + lane], hb);
      H[((size_t)vc * NRAT + r) * DD + lane] = f2bf(fmaxf(av + hb, 0.f));
    }
  } else if (b < 1064) {
    const int d = b - 1000;
    float acc = 0.f;
#pragma unroll 8
    for (int t = 0; t < DD; ++t) acc = fmaf(Wq[lane * DD + t], Wk[d * DD + t], acc);
    M1T[d * DD + lane] = f2bf(acc);
  } else if (b < 1128) {
    const int d = b - 1064;
    float acc = 0.f;
#pragma unroll 8
    for (int t = 0; t < DD; ++t) acc = fmaf(Wv[lane * DD + t], Wo[t * DD + d], acc);
    WVOT[d * DD + lane] = f2bf(acc);
  } else {
    float a1 = 0.f, a2 = bo[lane];
#pragma unroll 8
    for (int t = 0; t < DD; ++t) {
      a1 = fmaf(Wk[lane * DD + t], bq[t], a1);
      a2 = fmaf(bv[t], Wo[t * DD + lane], a2);
    }
    BKQ[lane] = a1;
    BVO[lane] = a2;
  }
}

// ---------------- main: 512 threads, 16 nodes per block, 2 nodes per wave ----------------
__global__ __launch_bounds__(512, 8) void vc_main(
    const int* __restrict__ nodes, const int* __restrict__ hvc,
    const int* __restrict__ hr, const float* __restrict__ v2e,
    const char* __restrict__ ws, float* __restrict__ out, int N) {
  const unsigned short* __restrict__ H = (const unsigned short*)(ws + OFF_H);
  const unsigned short* __restrict__ M1T = (const unsigned short*)(ws + OFF_M1T);
  const unsigned short* __restrict__ WVOT = (const unsigned short*)(ws + OFF_WVOT);
  const float* __restrict__ BKQ = (const float*)(ws + OFF_BKQ);
  const float* __restrict__ BVO = (const float*)(ws + OFF_BVO);

  __shared__ float gS[16][68];    // [node][d], 68-stride: worst 2-way bank alias (free)
  __shared__ float ctxS[16][68];

  const int tid = threadIdx.x;
  const int wid = tid >> 6;    // 0..7
  const int lane = tid & 63;
  const int kg = lane >> 4;    // 0..3
  const int rw = lane & 15;    // 0..15
  const int nb = blockIdx.x * 16;

  // ---- prefetch this wave's 2 nodes' history indices (before barrier) ----
  const int lidx = (lane < LL) ? lane : 0;
  const int nA = min(nb + wid * 2 + 0, N - 1);
  const int nB = min(nb + wid * 2 + 1, N - 1);
  const int idxA = hvc[(size_t)nA * LL + lidx] * NRAT + hr[(size_t)nA * LL + lidx];
  const int idxB = hvc[(size_t)nB * LL + lidx] * NRAT + hr[(size_t)nB * LL + lidx];

  // ---- G = X @ M1 + bkq : waves 0-3, wave w computes d-quarter n0==w ----
  if (wid < 4) {
    const int node_id = nodes[min(nb + rw, N - 1)];
    const float* __restrict__ xrow = v2e + (size_t)node_id * DD;
    short8 xa[2];
#pragma unroll
    for (int ks = 0; ks < 2; ++ks) {
      const float4 f0 = *(const float4*)(xrow + ks * 32 + kg * 8);
      const float4 f1 = *(const float4*)(xrow + ks * 32 + kg * 8 + 4);
      short8 t;
      t[0] = (short)f2bf(f0.x); t[1] = (short)f2bf(f0.y);
      t[2] = (short)f2bf(f0.z); t[3] = (short)f2bf(f0.w);
      t[4] = (short)f2bf(f1.x); t[5] = (short)f2bf(f1.y);
      t[6] = (short)f2bf(f1.z); t[7] = (short)f2bf(f1.w);
      xa[ks] = t;
    }
    const int n0 = wid;
    f32x4 a = {0.f, 0.f, 0.f, 0.f};
#pragma unroll
    for (int ks = 0; ks < 2; ++ks) {
      const short8 bf = *(const short8*)(M1T + (n0 * 16 + rw) * DD + ks * 32 + kg * 8);
      a = __builtin_amdgcn_mfma_f32_16x16x32_bf16(xa[ks], bf, a, 0, 0, 0);
    }
    const float bkqv = BKQ[n0 * 16 + rw];
#pragma unroll
    for (int r = 0; r < 4; ++r) gS[kg * 4 + r][n0 * 16 + rw] = a[r] + bkqv;
  }
  __syncthreads();

  // ---- per-node gather phases: 2 nodes per wave ----
#pragma unroll
  for (int nn = 0; nn < 2; ++nn) {
    const int idx = nn ? idxB : idxA;
    const int myrow = wid * 2 + nn;

    // scores: lane = history slot l, dot(H[idx], g) over 64 dims, 4 accumulators
    const uint4* __restrict__ hp = (const uint4*)(H + (size_t)idx * DD);
    const float4* __restrict__ gp = (const float4*)(&gS[myrow][0]);
    float s0 = 0.f, s1 = 0.f, s2 = 0.f, s3 = 0.f;
#pragma unroll
    for (int c = 0; c < 8; ++c) {
      const uint4 u = hp[c];
      const float4 g0 = gp[2 * c];
      const float4 g1 = gp[2 * c + 1];
      s0 = fmaf(bflo(u.x), g0.x, s0); s1 = fmaf(bfhi(u.x), g0.y, s1);
      s2 = fmaf(bflo(u.y), g0.z, s2); s3 = fmaf(bfhi(u.y), g0.w, s3);
      s0 = fmaf(bflo(u.z), g1.x, s0); s1 = fmaf(bfhi(u.z), g1.y, s1);
      s2 = fmaf(bflo(u.w), g1.z, s2); s3 = fmaf(bfhi(u.w), g1.w, s3);
    }
    float s = ((s0 + s1) + (s2 + s3)) * 0.125f;   // q·bk const over l -> cancels
    s = (lane < LL) ? s : -INFINITY;
    const float m = wave_max(s);
    const float e = __expf(s - m);
    const float invZ = 1.f / wave_sum(e);

    // ctx: lane = d, sum_l e_l * H[idx_l][d], 2 accumulators
    float c0 = 0.f, c1 = 0.f;
#pragma unroll 5
    for (int l = 0; l < LL; l += 2) {
      const int siA = __builtin_amdgcn_readlane(idx, l);
      const float eA = rlanef(e, l);
      const int siB = __builtin_amdgcn_readlane(idx, l + 1);
      const float eB = rlanef(e, l + 1);
      const unsigned short hA = H[(size_t)siA * DD + lane];
      const unsigned short hB = H[(size_t)siB * DD + lane];
      c0 = fmaf(__uint_as_float(((unsigned int)hA) << 16), eA, c0);
      c1 = fmaf(__uint_as_float(((unsigned int)hB) << 16), eB, c1);
    }
    ctxS[myrow][lane] = (c0 + c1) * invZ;
  }
  __syncthreads();

  // ---- OUT = CTX @ Wvo + bvo : waves 0-3, wave w computes d-quarter n0==w ----
  if (wid < 4) {
    short8 ca[2];
#pragma unroll
    for (int ks = 0; ks < 2; ++ks) {
      const float* __restrict__ cp = &ctxS[rw][ks * 32 + kg * 8];
      const float4 f0 = *(const float4*)(cp);
      const float4 f1 = *(const float4*)(cp + 4);
      short8 t;
      t[0] = (short)f2bf(f0.x); t[1] = (short)f2bf(f0.y);
      t[2] = (short)f2bf(f0.z); t[3] = (short)f2bf(f0.w);
      t[4] = (short)f2bf(f1.x); t[5] = (short)f2bf(f1.y);
      t[6] = (short)f2bf(f1.z); t[7] = (short)f2bf(f1.w);
      ca[ks] = t;
    }
    const int n0 = wid;
    f32x4 a = {0.f, 0.f, 0.f, 0.f};
#pragma unroll
    for (int ks = 0; ks < 2; ++ks) {
      const short8 bf = *(const short8*)(WVOT + (n0 * 16 + rw) * DD + ks * 32 + kg * 8);
      a = __builtin_amdgcn_mfma_f32_16x16x32_bf16(ca[ks], bf, a, 0, 0, 0);
    }
    const float bvov = BVO[n0 * 16 + rw];
#pragma unroll
    for (int r = 0; r < 4; ++r) {
      const int node = nb + kg * 4 + r;
      if (node < N) out[(size_t)node * DD + n0 * 16 + rw] = a[r] + bvov;
    }
  }
}

extern "C" void kernel_launch(void* const* d_in, const int* in_sizes, int n_in,
                              void* d_out, int out_size, void* d_ws, size_t ws_size,
                              hipStream_t stream) {
  const int* nodes = (const int*)d_in[0];
  const int* hvc = (const int*)d_in[1];
  const int* hr = (const int*)d_in[2];
  const float* c2e = (const float*)d_in[3];
  const float* v2e = (const float*)d_in[4];
  const float* r2e = (const float*)d_in[5];
  const float* W1 = (const float*)d_in[6];
  const float* b1 = (const float*)d_in[7];
  const float* Wq = (const float*)d_in[8];
  const float* bq = (const float*)d_in[9];
  const float* Wk = (const float*)d_in[10];
  const float* bk = (const float*)d_in[11];  // unused: q·bk cancels in softmax
  const float* Wv = (const float*)d_in[12];
  const float* bv = (const float*)d_in[13];
  const float* Wo = (const float*)d_in[14];
  const float* bo = (const float*)d_in[15];
  (void)bk;
  float* out = (float*)d_out;
  char* ws = (char*)d_ws;

  const int N = in_sizes[0];

  prep_kernel<<<1129, 64, 0, stream>>>(c2e, r2e, W1, b1, Wq, bq, Wk, Wv, Wo, bv, bo, ws);
  vc_main<<<(N + 15) / 16, 512, 0, stream>>>(nodes, hvc, hr, v2e, ws, out, N);
}